// Round 7
// baseline (233.845 us; speedup 1.0000x reference)
//
#include <hip/hip_runtime.h>
#include <hip/hip_bf16.h>

// m=64 sample rows + 1 target row = 65 rows of Nk = 524288 f32 each.
// Score reduces to the 65x65 Gram matrix + O(m^2) scalar epilogue.
// time_points (d_in[2]) cancels in all pairwise differences -> unused.
//
// R7: CACHE-SET DE-PHASING via two-pass repack. R1-R6: four structurally
// different gram loops (LDS-staged, register-direct, interleaved, blocked)
// all pinned at ~1.7 TB/s while fills sustain 6.9 -> the invariant is
// reading 65 rows at the same k with row stride EXACTLY 2 MiB: all 65
// same-k lines map to the same L1/L2 set (2MiB >> any index span) ->
// set thrash/MSHR serialization, independent of load mechanism.
// Fix: (a) pack_k streams X row-LINEARLY (proven-fast pattern) and writes
// bf16 chunk-major P[c2][66][64] (8448 B/chunk, non-pow2 stride);
// (b) gram_b reads each 8.3 KB chunk as one contiguous block into
// registers (no LDS, no swizzle, L2/L3-hot) and runs 2x15 MFMAs.
#define NROW 65
#define GP   80            // padded gram dim (5 tiles of 16)
#define GE   (GP * GP)     // 6400 f32
#define C2F  64            // f32 (k) per chunk2 (two MFMA K-steps)
#define CROW 66            // rows per packed chunk (65 real + 1 pad)
#define CELEM (CROW * C2F) // 4224 bf16 elems per chunk2 (8448 B)
#define TPB  256
#define GRID_B 512         // gram_b blocks (4 waves each)

typedef float  f32x4  __attribute__((ext_vector_type(4)));
typedef __bf16 bf16x8 __attribute__((ext_vector_type(8)));

// Pass a: row-linear read of X/T (f32), write bf16 chunk-major.
// job = blockIdx.x: row = job>>8 (0..64), strip = job&255 (32 chunk2s).
// Thread: 8 consecutive f32 -> 8 bf16 (16B store).
// Wave reads 2KB contiguous; writes 8 x 128B segments at 8448B stride.
__global__ __launch_bounds__(TPB) void pack_k(
    const float* __restrict__ X, const float* __restrict__ T,
    __bf16* __restrict__ P, int Nk)
{
  const int job   = blockIdx.x;
  const int row   = job >> 8;
  const int strip = job & 255;
  const int tid   = threadIdx.x;
  const int c2    = strip * 32 + (tid >> 3);
  const int klo   = (tid & 7) * 8;

  const float* src = ((row < 64) ? (X + (size_t)row * Nk) : T)
                     + (size_t)c2 * C2F + klo;
  f32x4 a = *(const f32x4*)src;
  f32x4 b = *(const f32x4*)(src + 4);
  bf16x8 h = (bf16x8){(__bf16)a.x, (__bf16)a.y, (__bf16)a.z, (__bf16)a.w,
                      (__bf16)b.x, (__bf16)b.y, (__bf16)b.z, (__bf16)b.w};
  *(bf16x8*)(P + (size_t)c2 * CELEM + row * C2F + klo) = h;
}

// Pass b: grid-stride waves over chunk2s; per chunk2: 10 direct 16B register
// loads (contiguous 8.3KB window, L2-hot), 2 K-steps x 15 upper-tri MFMAs.
// Row 65 = pad garbage (0xAA poison -> tiny finite bf16), feeds only
// discarded (i>64 or j>64) gram entries.
__global__ __launch_bounds__(TPB) void gram_b(
    const __bf16* __restrict__ P,
    float* __restrict__ S,         // [gridDim.x][GE] slice output
    int nc2)
{
  __shared__ float gl[GE];
  const int tid  = threadIdx.x;
  const int wv   = tid >> 6;
  const int lane = tid & 63;
  const int lr   = lane & 15, kg = lane >> 4;

  f32x4 acc[15];
#pragma unroll
  for (int i = 0; i < 15; ++i) acc[i] = (f32x4){0.f, 0.f, 0.f, 0.f};

  const int nw = gridDim.x * (TPB / 64);
  const int gw = blockIdx.x * (TPB / 64) + wv;

  for (int c2 = gw; c2 < nc2; c2 += nw) {
    const __bf16* base = P + (size_t)c2 * CELEM;
    bf16x8 f[2][5];
#pragma unroll
    for (int s = 0; s < 2; ++s)
#pragma unroll
      for (int t = 0; t < 5; ++t) {
        int r = t * 16 + lr; if (r > 65) r = 65;
        f[s][t] = *(const bf16x8*)(base + r * C2F + s * 32 + kg * 8);
      }
#pragma unroll
    for (int s = 0; s < 2; ++s)
#pragma unroll
      for (int I = 0; I < 5; ++I)
#pragma unroll
        for (int J = I; J < 5; ++J) {
          const int idx = I * 5 + J - (I * (I + 1)) / 2;
          acc[idx] = __builtin_amdgcn_mfma_f32_16x16x32_bf16(f[s][I], f[s][J], acc[idx], 0, 0, 0);
        }
  }

  // Atomic-free block reduction (serialized wave rounds), coalesced store.
  for (int e = tid; e < GE; e += TPB) gl[e] = 0.f;
  __syncthreads();
  for (int w = 0; w < 4; ++w) {
    if (wv == w) {
#pragma unroll
      for (int I = 0; I < 5; ++I)
#pragma unroll
        for (int J = I; J < 5; ++J) {
          const int idx = I * 5 + J - (I * (I + 1)) / 2;
#pragma unroll
          for (int r = 0; r < 4; ++r) {
            const int grow = I * 16 + kg * 4 + r;   // C/D: row=(lane>>4)*4+reg
            const int gcol = J * 16 + lr;           //      col=lane&15
            gl[grow * GP + gcol] += acc[idx][r];
          }
        }
    }
    __syncthreads();
  }
  float* dst = S + (size_t)blockIdx.x * GE;
  for (int e = tid; e < GE; e += TPB) dst[e] = gl[e];
}

// R4 parallel slice reduction (measured: 121.7 us -> ~8 us).
#define RBLK 64
__global__ __launch_bounds__(256) void reduce_k(
    const float* __restrict__ S, float* __restrict__ G, int nsl)
{
  __shared__ float ps[4][RBLK];
  const int tid = threadIdx.x;
  const int e0  = blockIdx.x * RBLK;
  const int el  = tid & (RBLK - 1);
  const int p   = tid >> 6;            // 0..3
  const float* base = S + (size_t)p * GE + (e0 + el);
  float s = 0.f;
  int i = p;
#pragma unroll 8
  for (; i + 32 <= nsl; i += 32) {
    s += base[0];
    s += base[(size_t)4  * GE];
    s += base[(size_t)8  * GE];
    s += base[(size_t)12 * GE];
    s += base[(size_t)16 * GE];
    s += base[(size_t)20 * GE];
    s += base[(size_t)24 * GE];
    s += base[(size_t)28 * GE];
    base += (size_t)32 * GE;
  }
  for (; i < nsl; i += 4) { s += base[0]; base += (size_t)4 * GE; }
  ps[p][el] = s;
  __syncthreads();
  if (tid < RBLK)
    G[e0 + tid] = ps[0][tid] + ps[1][tid] + ps[2][tid] + ps[3][tid];
}

__global__ __launch_bounds__(256) void epilogue_k(
    const float* __restrict__ G, float* __restrict__ out)
{
  __shared__ float gl[GE];
  __shared__ float rx[4], rt[4];
  const int tid = threadIdx.x;
  for (int e = tid; e < GE; e += 256) gl[e] = G[e];
  __syncthreads();

  float accX = 0.f, accT = 0.f;
  for (int e = tid; e < GE; e += 256) {
    int i = e / GP, j = e % GP;
    if (j >= NROW || i >= j) continue;           // upper triangle, i<j
    float g  = gl[e];
    float d2 = gl[i * GP + i] + gl[j * GP + j] - 2.f * g;
    if (j < 64) accX += expf(-fmaxf(d2, 0.f));   // pair term (ref clamps d2)
    else        accT += expf(-d2);               // target term (no clamp)
  }
#pragma unroll
  for (int off = 32; off > 0; off >>= 1) {
    accX += __shfl_down(accX, off);
    accT += __shfl_down(accT, off);
  }
  const int wv = tid >> 6, lane = tid & 63;
  if (lane == 0) { rx[wv] = accX; rt[wv] = accT; }
  __syncthreads();
  if (tid == 0) {
    float sx = rx[0] + rx[1] + rx[2] + rx[3];
    float st = rt[0] + rt[1] + rt[2] + rt[3];
    // cross = (LAMBDA/2) * 2*sx / (m(m-1)) = sx/8064
    float score = sx / 8064.f - st / 64.f;
    score = fminf(fmaxf(score, -10.f), 10.f);
    out[0] = score;
  }
}

extern "C" void kernel_launch(void* const* d_in, const int* in_sizes, int n_in,
                              void* d_out, int out_size, void* d_ws, size_t ws_size,
                              hipStream_t stream) {
  const float* X = (const float*)d_in[0];   // generated_samples [64,4096,128]
  const float* T = (const float*)d_in[1];   // target_sample [4096,128]
  float* out = (float*)d_out;

  const int Nk  = in_sizes[1];              // 524288
  const int nc2 = Nk / C2F;                 // 8192 chunk2s

  // ws layout: P packed bf16 [nc2][66][64] | S slices [nsl][GE] | G [GE]
  size_t p_bytes = (size_t)nc2 * CELEM * sizeof(__bf16);      // ~69.2 MB
  p_bytes = (p_bytes + 255) & ~(size_t)255;
  __bf16* P = (__bf16*)d_ws;
  size_t rem = (ws_size > p_bytes) ? (ws_size - p_bytes) : 0;
  int nsl = (int)(rem / (GE * sizeof(float))) - 1;
  if (nsl > GRID_B) nsl = GRID_B;
  if (nsl < 1) nsl = 1;
  float* S = (float*)((char*)d_ws + p_bytes);
  float* G = S + (size_t)nsl * GE;

  pack_k<<<65 * 256, TPB, 0, stream>>>(X, T, P, Nk);
  gram_b<<<nsl, TPB, 0, stream>>>(P, S, nc2);
  reduce_k<<<(GE / RBLK), 256, 0, stream>>>(S, G, nsl);
  epilogue_k<<<1, 256, 0, stream>>>(G, out);
}

// Round 8
// 221.760 us; speedup vs baseline: 1.0545x; 1.0545x over previous
//
#include <hip/hip_runtime.h>
#include <hip/hip_bf16.h>

// m=64 sample rows + 1 target row = 65 rows of Nk = 524288 f32 each.
// Score reduces to the 65x65 Gram matrix + O(m^2) scalar epilogue.
// time_points (d_in[2]) cancels in all pairwise differences -> unused.
//
// R8 = DIAGNOSTIC: R5 structure (best total, 210 us), but gram_k sweeps K
// TWICE accumulating 2G (reduce_k scales by 0.5 -- binary exact). Purpose:
// push gram_k's duration (~150 us) above the 80-us ws-poison fills so it
// finally appears in the top-5 WITH counters. FETCH_SIZE readout:
//   ~272 MB  -> reads truly come from HBM; HBM-path inefficiency theory.
//   <<136 MB -> reads served by L3; L2-miss/MSHR path is the ~1.7 TB/s cap.
// VALUBusy/MfmaUtil/Occupancy rule issue-bound and concurrency theories.
#define NROW 65
#define GP   80            // padded gram dim (5 tiles of 16)
#define GE   (GP * GP)     // 6400 f32
#define CHF  32            // f32 per row per chunk (one MFMA K-step)
#define ROWB 128           // bytes per LDS row (CHF*4)
#define NRB  66            // rows per buffer: 65 real + 1 garbage (reads clamp)
#define BUFB (NRB * ROWB)  // 8448 B
#define WBUF (2 * BUFB)    // per-wave double buffer
#define TPB  256           // 4 waves
#define GRID_MAX 512
#define NREP 2             // K-sweep repetitions (acc = NREP * G)

typedef float  f32x4  __attribute__((ext_vector_type(4)));
typedef __bf16 bf16x8 __attribute__((ext_vector_type(8)));

__device__ __forceinline__ void gl_lds16(const void* g, void* l) {
  __builtin_amdgcn_global_load_lds(
      (const __attribute__((address_space(1))) void*)g,
      (__attribute__((address_space(3))) void*)l, 16, 0, 0);
}

__global__ __launch_bounds__(TPB) void gram_k(
    const float* __restrict__ X,   // [64][Nk]
    const float* __restrict__ T,   // [Nk]
    float* __restrict__ S,         // [gridDim.x][GE] slice output
    int Nk, int nch)
{
  // 4 waves x 16896 B = 67584 B; tail reduction reuses the first 25600 B.
  __shared__ __align__(16) char smem[4 * WBUF];
  const int tid  = threadIdx.x;
  const int wv   = tid >> 6;
  const int lane = tid & 63;
  const int lr   = lane & 15, kg = lane >> 4;
  const size_t Nkb = (size_t)Nk * 4;

  char* myb = smem + wv * WBUF;

  f32x4 acc[15];
#pragma unroll
  for (int i = 0; i < 15; ++i) acc[i] = (f32x4){0.f, 0.f, 0.f, 0.f};

  // Stage chunk c into this wave's buffer: 8 instrs x 8 rows x 128 B + 1
  // partial instr for row 64 (target). LDS dest is linear (gload_lds writes
  // base + lane*16); source is pre-swizzled so physical 16B-slot p of row r
  // holds global slot p^(r&7)  (rule 21: linear dest + inv-swz src + swz read).
  auto stage = [&](char* buf, int c) {
    const size_t colb = (size_t)c * ROWB;
#pragma unroll
    for (int i = 0; i < 8; ++i) {
      const int r  = 8 * i + (lane >> 3);
      const int ss = (lane & 7) ^ ((lane >> 3) & 7);   // (l&7)^(r&7)
      const char* src = (const char*)X + (size_t)r * Nkb + colb + ss * 16;
      gl_lds16(src, buf + i * 1024);
    }
    if (lane < 8) {                    // row 64; (64&7)=0 -> no swizzle
      const char* src = (const char*)T + colb + lane * 16;
      gl_lds16(src, buf + 64 * ROWB);
    }
  };

  const int nwaves = gridDim.x * (TPB / 64);
  const int gw = blockIdx.x * (TPB / 64) + wv;

  for (int rep = 0; rep < NREP; ++rep) {
    int c = gw;
    stage(myb, c);
    int it = 0;
    while (true) {
      char* cur = myb + (it & 1) * BUFB;
      char* nxt = myb + ((it & 1) ^ 1) * BUFB;
      const int cn = c + nwaves;
      const bool hn = cn < nch;
      // Previous iteration's ds_reads consumed; issue next-chunk loads so
      // they fly during this chunk's compute.
      asm volatile("s_waitcnt lgkmcnt(0)" ::: "memory");
      __builtin_amdgcn_sched_barrier(0);
      if (hn) stage(nxt, cn);
      if (hn) asm volatile("s_waitcnt vmcnt(9)" ::: "memory");  // cur complete
      else    asm volatile("s_waitcnt vmcnt(0)" ::: "memory");
      __builtin_amdgcn_sched_barrier(0);

      // Fragments: tile t, lane holds 8 f32 of row t*16+lr at float-offset
      // kg*8 within the 32-f32 chunk. Rows >65 clamp to garbage row 65 ->
      // pollutes only G entries with i or j >= 65 (discarded by epilogue).
      bf16x8 f[5];
#pragma unroll
      for (int t = 0; t < 5; ++t) {
        int r = t * 16 + lr; if (r > 65) r = 65;
        const char* rb = cur + r * ROWB;
        const int sw = (r & 7) << 4;
        f32x4 a = *(const f32x4*)(rb + ((kg * 32) ^ sw));
        f32x4 b = *(const f32x4*)(rb + ((kg * 32 + 16) ^ sw));
        f[t] = (bf16x8){(__bf16)a.x, (__bf16)a.y, (__bf16)a.z, (__bf16)a.w,
                        (__bf16)b.x, (__bf16)b.y, (__bf16)b.z, (__bf16)b.w};
      }
#pragma unroll
      for (int I = 0; I < 5; ++I)
#pragma unroll
        for (int J = I; J < 5; ++J) {
          const int idx = I * 5 + J - (I * (I + 1)) / 2;
          acc[idx] = __builtin_amdgcn_mfma_f32_16x16x32_bf16(f[I], f[J], acc[idx], 0, 0, 0);
        }
      if (!hn) break;
      c = cn; ++it;
    }
  }

  // Atomic-free block reduction: serialized wave rounds into LDS [80][80]
  // (reuses staging memory), then coalesced store of this block's slice.
  float* gl = (float*)smem;
  __syncthreads();
  for (int e = tid; e < GE; e += TPB) gl[e] = 0.f;
  __syncthreads();
  for (int w = 0; w < 4; ++w) {
    if (wv == w) {
#pragma unroll
      for (int I = 0; I < 5; ++I)
#pragma unroll
        for (int J = I; J < 5; ++J) {
          const int idx = I * 5 + J - (I * (I + 1)) / 2;
#pragma unroll
          for (int r = 0; r < 4; ++r) {
            const int grow = I * 16 + kg * 4 + r;   // C/D: row=(lane>>4)*4+reg
            const int gcol = J * 16 + lr;           //      col=lane&15
            gl[grow * GP + gcol] += acc[idx][r];
          }
        }
    }
    __syncthreads();
  }
  float* dst = S + (size_t)blockIdx.x * GE;
  for (int e = tid; e < GE; e += TPB) dst[e] = gl[e];
}

// R4 parallel slice reduction (measured: 121.7 us -> ~8 us).
// Scales by 1/NREP to undo the diagnostic K-sweep repetition (exact in f32).
#define RBLK 64
__global__ __launch_bounds__(256) void reduce_k(
    const float* __restrict__ S, float* __restrict__ G, int nsl)
{
  __shared__ float ps[4][RBLK];
  const int tid = threadIdx.x;
  const int e0  = blockIdx.x * RBLK;
  const int el  = tid & (RBLK - 1);
  const int p   = tid >> 6;            // 0..3
  const float* base = S + (size_t)p * GE + (e0 + el);
  float s = 0.f;
  int i = p;
#pragma unroll 8
  for (; i + 32 <= nsl; i += 32) {
    s += base[0];
    s += base[(size_t)4  * GE];
    s += base[(size_t)8  * GE];
    s += base[(size_t)12 * GE];
    s += base[(size_t)16 * GE];
    s += base[(size_t)20 * GE];
    s += base[(size_t)24 * GE];
    s += base[(size_t)28 * GE];
    base += (size_t)32 * GE;
  }
  for (; i < nsl; i += 4) { s += base[0]; base += (size_t)4 * GE; }
  ps[p][el] = s;
  __syncthreads();
  if (tid < RBLK)
    G[e0 + tid] = (1.0f / NREP) *
                  (ps[0][tid] + ps[1][tid] + ps[2][tid] + ps[3][tid]);
}

__global__ __launch_bounds__(256) void epilogue_k(
    const float* __restrict__ G, float* __restrict__ out)
{
  __shared__ float gl[GE];
  __shared__ float rx[4], rt[4];
  const int tid = threadIdx.x;
  for (int e = tid; e < GE; e += 256) gl[e] = G[e];
  __syncthreads();

  float accX = 0.f, accT = 0.f;
  for (int e = tid; e < GE; e += 256) {
    int i = e / GP, j = e % GP;
    if (j >= NROW || i >= j) continue;           // upper triangle, i<j
    float g  = gl[e];
    float d2 = gl[i * GP + i] + gl[j * GP + j] - 2.f * g;
    if (j < 64) accX += expf(-fmaxf(d2, 0.f));   // pair term (ref clamps d2)
    else        accT += expf(-d2);               // target term (no clamp)
  }
#pragma unroll
  for (int off = 32; off > 0; off >>= 1) {
    accX += __shfl_down(accX, off);
    accT += __shfl_down(accT, off);
  }
  const int wv = tid >> 6, lane = tid & 63;
  if (lane == 0) { rx[wv] = accX; rt[wv] = accT; }
  __syncthreads();
  if (tid == 0) {
    float sx = rx[0] + rx[1] + rx[2] + rx[3];
    float st = rt[0] + rt[1] + rt[2] + rt[3];
    // cross = (LAMBDA/2) * 2*sx / (m(m-1)) = sx/8064
    float score = sx / 8064.f - st / 64.f;
    score = fminf(fmaxf(score, -10.f), 10.f);
    out[0] = score;
  }
}

extern "C" void kernel_launch(void* const* d_in, const int* in_sizes, int n_in,
                              void* d_out, int out_size, void* d_ws, size_t ws_size,
                              hipStream_t stream) {
  const float* X = (const float*)d_in[0];   // generated_samples [64,4096,128]
  const float* T = (const float*)d_in[1];   // target_sample [4096,128]
  float* out = (float*)d_out;

  const int Nk  = in_sizes[1];              // 524288
  const int nch = Nk / CHF;                 // 16384 chunks of 32 f32

  // ws layout: [nsl][GE] slices | [GE] final G
  int nsl = (int)(ws_size / (GE * sizeof(float))) - 1;
  if (nsl > GRID_MAX) nsl = GRID_MAX;
  if (nsl < 1) nsl = 1;
  float* S = (float*)d_ws;
  float* G = S + (size_t)nsl * GE;

  gram_k<<<nsl, TPB, 0, stream>>>(X, T, S, Nk, nch);
  reduce_k<<<(GE / RBLK), 256, 0, stream>>>(S, G, nsl);
  epilogue_k<<<1, 256, 0, stream>>>(G, out);
}

// Round 9
// 201.843 us; speedup vs baseline: 1.1585x; 1.0987x over previous
//
#include <hip/hip_runtime.h>
#include <hip/hip_bf16.h>

// m=64 sample rows + 1 target row = 65 rows of Nk = 524288 f32 each.
// Score reduces to the 65x65 Gram matrix + O(m^2) scalar epilogue.
// time_points (d_in[2]) cancels in all pairwise differences -> unused.
//
// R9 = R5 + NON-TEMPORAL staging loads (single variable vs R5's 209.97 us).
// R8 diagnostic: 2nd K-sweep of the same data cost +11.8 us (11.5 TB/s) ->
// loop machinery is fine; the 1st (cold) sweep runs at ~2 TB/s. Theory: the
// harness's 512-MB 0xAA ws-poison + 272-MB input restore leave L2/L3 full
// of dirty lines; every cold-miss ALLOCATION forces a dirty victim
// writeback (doubles HBM traffic, serializes on drain). Fix: aux=2 (NT bit,
// gfx940+ cpol) on global_load_lds -> no allocation, no eviction. Input is
// read exactly once, so NT is semantically ideal.
#define NROW 65
#define GP   80            // padded gram dim (5 tiles of 16)
#define GE   (GP * GP)     // 6400 f32
#define CHF  32            // f32 per row per chunk (one MFMA K-step)
#define ROWB 128           // bytes per LDS row (CHF*4)
#define NRB  66            // rows per buffer: 65 real + 1 garbage (reads clamp)
#define BUFB (NRB * ROWB)  // 8448 B
#define WBUF (2 * BUFB)    // per-wave double buffer
#define TPB  256           // 4 waves
#define GRID_MAX 512

typedef float  f32x4  __attribute__((ext_vector_type(4)));
typedef __bf16 bf16x8 __attribute__((ext_vector_type(8)));

__device__ __forceinline__ void gl_lds16_nt(const void* g, void* l) {
  __builtin_amdgcn_global_load_lds(
      (const __attribute__((address_space(1))) void*)g,
      (__attribute__((address_space(3))) void*)l, 16, 0, /*cpol NT=*/2);
}

__global__ __launch_bounds__(TPB) void gram_k(
    const float* __restrict__ X,   // [64][Nk]
    const float* __restrict__ T,   // [Nk]
    float* __restrict__ S,         // [gridDim.x][GE] slice output
    int Nk, int nch)
{
  // 4 waves x 16896 B = 67584 B; tail reduction reuses the first 25600 B.
  __shared__ __align__(16) char smem[4 * WBUF];
  const int tid  = threadIdx.x;
  const int wv   = tid >> 6;
  const int lane = tid & 63;
  const int lr   = lane & 15, kg = lane >> 4;
  const size_t Nkb = (size_t)Nk * 4;

  char* myb = smem + wv * WBUF;

  f32x4 acc[15];
#pragma unroll
  for (int i = 0; i < 15; ++i) acc[i] = (f32x4){0.f, 0.f, 0.f, 0.f};

  // Stage chunk c into this wave's buffer: 8 instrs x 8 rows x 128 B + 1
  // partial instr for row 64 (target). LDS dest is linear (gload_lds writes
  // base + lane*16); source is pre-swizzled so physical 16B-slot p of row r
  // holds global slot p^(r&7)  (rule 21: linear dest + inv-swz src + swz read).
  auto stage = [&](char* buf, int c) {
    const size_t colb = (size_t)c * ROWB;
#pragma unroll
    for (int i = 0; i < 8; ++i) {
      const int r  = 8 * i + (lane >> 3);
      const int ss = (lane & 7) ^ ((lane >> 3) & 7);   // (l&7)^(r&7)
      const char* src = (const char*)X + (size_t)r * Nkb + colb + ss * 16;
      gl_lds16_nt(src, buf + i * 1024);
    }
    if (lane < 8) {                    // row 64; (64&7)=0 -> no swizzle
      const char* src = (const char*)T + colb + lane * 16;
      gl_lds16_nt(src, buf + 64 * ROWB);
    }
  };

  const int nwaves = gridDim.x * (TPB / 64);
  int c = blockIdx.x * (TPB / 64) + wv;
  stage(myb, c);
  int it = 0;
  while (true) {
    char* cur = myb + (it & 1) * BUFB;
    char* nxt = myb + ((it & 1) ^ 1) * BUFB;
    const int cn = c + nwaves;
    const bool hn = cn < nch;
    // Previous iteration's ds_reads consumed; issue next-chunk loads so
    // they fly during this chunk's compute.
    asm volatile("s_waitcnt lgkmcnt(0)" ::: "memory");
    __builtin_amdgcn_sched_barrier(0);
    if (hn) stage(nxt, cn);
    if (hn) asm volatile("s_waitcnt vmcnt(9)" ::: "memory");  // cur complete
    else    asm volatile("s_waitcnt vmcnt(0)" ::: "memory");
    __builtin_amdgcn_sched_barrier(0);

    // Fragments: tile t, lane holds 8 f32 of row t*16+lr at float-offset
    // kg*8 within the 32-f32 chunk. Rows >65 clamp to garbage row 65 ->
    // pollutes only G entries with i or j >= 65 (each MFMA output element
    // (i,j) touches only A-row i / B-row j), which epilogue discards.
    bf16x8 f[5];
#pragma unroll
    for (int t = 0; t < 5; ++t) {
      int r = t * 16 + lr; if (r > 65) r = 65;
      const char* rb = cur + r * ROWB;
      const int sw = (r & 7) << 4;
      f32x4 a = *(const f32x4*)(rb + ((kg * 32) ^ sw));
      f32x4 b = *(const f32x4*)(rb + ((kg * 32 + 16) ^ sw));
      f[t] = (bf16x8){(__bf16)a.x, (__bf16)a.y, (__bf16)a.z, (__bf16)a.w,
                      (__bf16)b.x, (__bf16)b.y, (__bf16)b.z, (__bf16)b.w};
    }
#pragma unroll
    for (int I = 0; I < 5; ++I)
#pragma unroll
      for (int J = I; J < 5; ++J) {
        const int idx = I * 5 + J - (I * (I + 1)) / 2;
        acc[idx] = __builtin_amdgcn_mfma_f32_16x16x32_bf16(f[I], f[J], acc[idx], 0, 0, 0);
      }
    if (!hn) break;
    c = cn; ++it;
  }

  // Atomic-free block reduction: serialized wave rounds into LDS [80][80]
  // (reuses staging memory), then coalesced store of this block's slice.
  float* gl = (float*)smem;
  __syncthreads();
  for (int e = tid; e < GE; e += TPB) gl[e] = 0.f;
  __syncthreads();
  for (int w = 0; w < 4; ++w) {
    if (wv == w) {
#pragma unroll
      for (int I = 0; I < 5; ++I)
#pragma unroll
        for (int J = I; J < 5; ++J) {
          const int idx = I * 5 + J - (I * (I + 1)) / 2;
#pragma unroll
          for (int r = 0; r < 4; ++r) {
            const int grow = I * 16 + kg * 4 + r;   // C/D: row=(lane>>4)*4+reg
            const int gcol = J * 16 + lr;           //      col=lane&15
            gl[grow * GP + gcol] += acc[idx][r];
          }
        }
    }
    __syncthreads();
  }
  float* dst = S + (size_t)blockIdx.x * GE;
  for (int e = tid; e < GE; e += TPB) dst[e] = gl[e];
}

// R4 parallel slice reduction (measured: 121.7 us -> ~8 us).
#define RBLK 64
__global__ __launch_bounds__(256) void reduce_k(
    const float* __restrict__ S, float* __restrict__ G, int nsl)
{
  __shared__ float ps[4][RBLK];
  const int tid = threadIdx.x;
  const int e0  = blockIdx.x * RBLK;
  const int el  = tid & (RBLK - 1);
  const int p   = tid >> 6;            // 0..3
  const float* base = S + (size_t)p * GE + (e0 + el);
  float s = 0.f;
  int i = p;
#pragma unroll 8
  for (; i + 32 <= nsl; i += 32) {
    s += base[0];
    s += base[(size_t)4  * GE];
    s += base[(size_t)8  * GE];
    s += base[(size_t)12 * GE];
    s += base[(size_t)16 * GE];
    s += base[(size_t)20 * GE];
    s += base[(size_t)24 * GE];
    s += base[(size_t)28 * GE];
    base += (size_t)32 * GE;
  }
  for (; i < nsl; i += 4) { s += base[0]; base += (size_t)4 * GE; }
  ps[p][el] = s;
  __syncthreads();
  if (tid < RBLK)
    G[e0 + tid] = ps[0][tid] + ps[1][tid] + ps[2][tid] + ps[3][tid];
}

__global__ __launch_bounds__(256) void epilogue_k(
    const float* __restrict__ G, float* __restrict__ out)
{
  __shared__ float gl[GE];
  __shared__ float rx[4], rt[4];
  const int tid = threadIdx.x;
  for (int e = tid; e < GE; e += 256) gl[e] = G[e];
  __syncthreads();

  float accX = 0.f, accT = 0.f;
  for (int e = tid; e < GE; e += 256) {
    int i = e / GP, j = e % GP;
    if (j >= NROW || i >= j) continue;           // upper triangle, i<j
    float g  = gl[e];
    float d2 = gl[i * GP + i] + gl[j * GP + j] - 2.f * g;
    if (j < 64) accX += expf(-fmaxf(d2, 0.f));   // pair term (ref clamps d2)
    else        accT += expf(-d2);               // target term (no clamp)
  }
#pragma unroll
  for (int off = 32; off > 0; off >>= 1) {
    accX += __shfl_down(accX, off);
    accT += __shfl_down(accT, off);
  }
  const int wv = tid >> 6, lane = tid & 63;
  if (lane == 0) { rx[wv] = accX; rt[wv] = accT; }
  __syncthreads();
  if (tid == 0) {
    float sx = rx[0] + rx[1] + rx[2] + rx[3];
    float st = rt[0] + rt[1] + rt[2] + rt[3];
    // cross = (LAMBDA/2) * 2*sx / (m(m-1)) = sx/8064
    float score = sx / 8064.f - st / 64.f;
    score = fminf(fmaxf(score, -10.f), 10.f);
    out[0] = score;
  }
}

extern "C" void kernel_launch(void* const* d_in, const int* in_sizes, int n_in,
                              void* d_out, int out_size, void* d_ws, size_t ws_size,
                              hipStream_t stream) {
  const float* X = (const float*)d_in[0];   // generated_samples [64,4096,128]
  const float* T = (const float*)d_in[1];   // target_sample [4096,128]
  float* out = (float*)d_out;

  const int Nk  = in_sizes[1];              // 524288
  const int nch = Nk / CHF;                 // 16384 chunks of 32 f32

  // ws layout: [nsl][GE] slices | [GE] final G
  int nsl = (int)(ws_size / (GE * sizeof(float))) - 1;
  if (nsl > GRID_MAX) nsl = GRID_MAX;
  if (nsl < 1) nsl = 1;
  float* S = (float*)d_ws;
  float* G = S + (size_t)nsl * GE;

  gram_k<<<nsl, TPB, 0, stream>>>(X, T, S, Nk, nch);
  reduce_k<<<(GE / RBLK), 256, 0, stream>>>(S, G, nsl);
  epilogue_k<<<1, 256, 0, stream>>>(G, out);
}